// Round 3
// baseline (377.309 us; speedup 1.0000x reference)
//
#include <hip/hip_runtime.h>
#include <cstdint>

typedef __attribute__((ext_vector_type(8))) _Float16 half8;   // 8 fp16 = 4 VGPRs
typedef __attribute__((ext_vector_type(16))) float   f32x16;  // 32x32 MFMA acc

#define BN 2
#define NN 16384
#define FH 64
#define FW 64
#define GH 256
#define GW 256
#define CC 128
#define M_TOTAL (4*BN*NN)    // 131072
#define MROWS 64
#define NBLK (M_TOTAL/MROWS) // 2048

// LDS layout (fp16 elems). Strides chosen so dword-stride % 32 == 4 or 20 -> even 32-bank spread.
#define SX 424               // X [64][416+pad]
#define SC 136               // H1 chunk [64][128+pad]
#define S2 264               // H2-half / H3 [64][256+pad]
#define S4 136               // H4 [64][128+pad]
#define OFF_HC 27136         // 64*SX
#define OFF_H3 16896         // 64*S2
#define LDS_ELEMS 35840      // 71680 B -> 2 blocks/CU

#define MFMA(a,b,c) __builtin_amdgcn_mfma_f32_32x32x16_f16((a),(b),(c),0,0,0)

static __device__ __forceinline__ f32x16 zero16() {
  f32x16 z;
#pragma unroll
  for (int i = 0; i < 16; ++i) z[i] = 0.f;
  return z;
}
static __device__ __forceinline__ half8 zero8() {
  half8 z;
#pragma unroll
  for (int e = 0; e < 8; ++e) z[e] = (_Float16)0.f;
  return z;
}

// ---------- weight fp32 -> packed fp16 32x16 MFMA A-fragment tiles ----------
// out[((jt*KT+kt)*64 + l)*8 + e] = W[jt*32 + (l&31)][kt*16 + (l>>5)*8 + e]
__global__ void pack_w(const float* __restrict__ wsrc, _Float16* __restrict__ out,
                       int NT, int K, int KT) {   // NT = NOUT/32
  int idx = blockIdx.x * 256 + threadIdx.x;
  int total = NT * KT * 64;
  if (idx >= total) return;
  int l = idx & 63;
  int t = idx >> 6;
  int kt = t % KT;
  int jt = t / KT;
  int row = jt * 32 + (l & 31);
  int k0 = kt * 16 + (l >> 5) * 8;
  _Float16* o = out + (size_t)idx * 8;
#pragma unroll
  for (int e = 0; e < 8; ++e) {
    int k = k0 + e;
    float v = (k < K) ? wsrc[(size_t)row * K + k] : 0.f;
    o[e] = (_Float16)v;
  }
}

// ---------- CHW -> HWC fp16 transpose ----------
__global__ void transpose_to_hwc(const float* __restrict__ in, _Float16* __restrict__ out,
                                 int C, int HH, int WW) {
  __shared__ float tile[32][33];
  const int xt = blockIdx.x, ct = blockIdx.y;
  const int bb = blockIdx.z / HH, y = blockIdx.z % HH;
  const int tx = threadIdx.x, ty = threadIdx.y;
  const int x0 = xt * 32, c0 = ct * 32;
#pragma unroll
  for (int i = 0; i < 4; ++i) {
    int c = c0 + ty + i * 8;
    tile[ty + i * 8][tx] = in[((size_t)(bb * C + c) * HH + y) * WW + x0 + tx];
  }
  __syncthreads();
#pragma unroll
  for (int i = 0; i < 4; ++i) {
    int x = x0 + ty + i * 8;
    out[((size_t)(bb * HH + y) * WW + x) * C + c0 + tx] = (_Float16)tile[tx][ty + i * 8];
  }
}

// ---------- store one 32x32 D-tile to LDS as H[m][n], bias+relu, 8B-vectorized ----------
// D layout (swapped: A=W, B=acts): col = m = lane&31, row n = (reg&3) + 8*(reg>>2) + 4*(lane>>5)
template<bool RELU>
static __device__ __forceinline__ void store_tile(const f32x16 acc, _Float16* lout, int ldo,
                                                  int row0, int col0,
                                                  const float* __restrict__ biasBase, int lane) {
  const int m = row0 + (lane & 31);
  const int s4 = (lane >> 5) * 4;
  _Float16* rp = lout + (size_t)m * ldo + col0 + s4;
  const float* bp = biasBase + s4;
#pragma unroll
  for (int g = 0; g < 4; ++g) {
    float4 bv = *(const float4*)(bp + 8 * g);
    union { _Float16 h[4]; unsigned long long u; } pk;
#pragma unroll
    for (int e = 0; e < 4; ++e) {
      float v = acc[4 * g + e] + ((const float*)&bv)[e];
      if (RELU) v = fmaxf(v, 0.f);
      pk.h[e] = (_Float16)v;
    }
    *(unsigned long long*)(rp + 8 * g) = pk.u;
  }
}

// ---------- fused main kernel ----------
__global__ __launch_bounds__(512, 4) void jiif_main(
    const float* __restrict__ coord,
    const _Float16* __restrict__ featT, const _Float16* __restrict__ hrT,
    const _Float16* __restrict__ lrT,
    const _Float16* __restrict__ W0p, const _Float16* __restrict__ W1p,
    const _Float16* __restrict__ W2p, const _Float16* __restrict__ W3p,
    const float* __restrict__ b0, const float* __restrict__ b1,
    const float* __restrict__ b2, const float* __restrict__ b3,
    const float* __restrict__ W4, const float* __restrict__ b4,
    float* __restrict__ preds) {
  extern __shared__ _Float16 lds[];
  const int tid = threadIdx.x;
  const int w = tid >> 6, lane = tid & 63;
  const int m0 = blockIdx.x * MROWS;
  _Float16* X   = lds;             // [64][SX]
  _Float16* Hc  = lds + OFF_HC;    // [64][SC]
  _Float16* H2r = lds;             // [64][S2] (two halves, sequentially)
  _Float16* H3r = lds + OFF_H3;    // [64][S2]
  _Float16* H4r = lds;             // [64][S4]

  // ---- gather: build X[64][416] ----
  {
    const int r = tid >> 3;       // 0..63
    const int g = tid & 7;        // 8 threads per row
    const int row = m0 + r;
    const int n = row & (NN - 1);
    const int bb = (row >> 14) & (BN - 1);
    const int k = row >> 15;      // offset index 0..3
    const float c0 = coord[((size_t)bb * NN + n) * 2 + 0];
    const float c1 = coord[((size_t)bb * NN + n) * 2 + 1];
    const float cy = c0 + ((k < 2) ? -1.f : 1.f) * (1.f / FH);
    const float cx = c1 + ((k & 1) ? 1.f : -1.f) * (1.f / FW);
    const float fy = rintf((cy + 1.f) * (FH * 0.5f) - 0.5f);
    const float fx = rintf((cx + 1.f) * (FW * 0.5f) - 0.5f);
    const bool vF = (fy >= 0.f) && (fy < (float)FH) && (fx >= 0.f) && (fx < (float)FW);
    const int iy = max(0, min(FH - 1, (int)fy));
    const int ix = max(0, min(FW - 1, (int)fx));
    const float gy = rintf((c0 + 1.f) * (GH * 0.5f) - 0.5f);
    const float gx = rintf((c1 + 1.f) * (GW * 0.5f) - 0.5f);
    const bool vH = (gy >= 0.f) && (gy < (float)GH) && (gx >= 0.f) && (gx < (float)GW);
    const int jy = max(0, min(GH - 1, (int)gy));
    const int jx = max(0, min(GW - 1, (int)gx));
    const _Float16* fp = featT + (size_t)((bb * FH + iy) * FW + ix) * CC;
    const _Float16* lp = lrT  + (size_t)((bb * FH + iy) * FW + ix) * CC;
    const _Float16* hp = hrT  + (size_t)((bb * GH + jy) * GW + jx) * CC;
    _Float16* xr = X + (size_t)r * SX;
#pragma unroll
    for (int t = 0; t < 2; ++t) {
      const int c8 = g * 16 + t * 8;
      half8 fv = vF ? *(const half8*)(fp + c8) : zero8();
      half8 lv = vF ? *(const half8*)(lp + c8) : zero8();
      half8 hv = vH ? *(const half8*)(hp + c8) : zero8();
      *(half8*)(xr + c8) = fv;
      *(half8*)(xr + CC + c8) = hv;
      half8 dv = hv - lv;
      *(half8*)(xr + 2 * CC + c8) = dv;
    }
    if (g == 0) {
      const float qc0 = vF ? (-1.f + (float)(2 * iy + 1) * (1.f / FH)) : 0.f;
      const float qc1 = vF ? (-1.f + (float)(2 * ix + 1) * (1.f / FW)) : 0.f;
      xr[384] = (_Float16)((c0 - qc0) * (float)FH);
      xr[385] = (_Float16)((c1 - qc1) * (float)FW);
#pragma unroll
      for (int c = 386; c < 416; ++c) xr[c] = (_Float16)0.f;
    }
  }
  __syncthreads();

  const int m31 = lane & 31;
  const int s8 = (lane >> 5) * 8;
  const int mt = w & 1;        // L0/L2/L3 m-tile
  const int jl = w >> 1;       // L0 jt_local 0..3

  // ---- fused L0 (chunks of 128 cols) -> L1 (K-chunks of 128) ----
  f32x16 a2_00 = zero16(), a2_01 = zero16(), a2_10 = zero16(), a2_11 = zero16();
#pragma unroll 1
  for (int c = 0; c < 8; ++c) {
    f32x16 a0 = zero16();
    {
      const _Float16* xb = X + (size_t)(mt * 32 + m31) * SX + s8;
      const _Float16* wb = W0p + ((size_t)((c * 4 + jl) * 26) * 64 + lane) * 8;
#pragma unroll 2
      for (int kt = 0; kt < 26; ++kt) {
        half8 A = *(const half8*)(wb + kt * 512);
        half8 B = *(const half8*)(xb + kt * 16);
        a0 = MFMA(A, B, a0);
      }
    }
    store_tile<true>(a0, Hc, SC, mt * 32, jl * 32, b0 + c * 128 + jl * 32, lane);
    __syncthreads();
    {
      const _Float16* hb0 = Hc + (size_t)m31 * SC + s8;
      const _Float16* hb1 = Hc + (size_t)(32 + m31) * SC + s8;
      const _Float16* w1a = W1p + ((size_t)(w * 64 + c * 8) * 64 + lane) * 8;
      const _Float16* w1b = W1p + ((size_t)((w + 8) * 64 + c * 8) * 64 + lane) * 8;
#pragma unroll 2
      for (int kt = 0; kt < 8; ++kt) {
        half8 A0 = *(const half8*)(w1a + kt * 512);
        half8 A1 = *(const half8*)(w1b + kt * 512);
        half8 B0 = *(const half8*)(hb0 + kt * 16);
        half8 B1 = *(const half8*)(hb1 + kt * 16);
        a2_00 = MFMA(A0, B0, a2_00);
        a2_01 = MFMA(A0, B1, a2_01);
        a2_10 = MFMA(A1, B0, a2_10);
        a2_11 = MFMA(A1, B1, a2_11);
      }
    }
    __syncthreads();
  }

  // ---- H2 in 2 halves, fused with L2 (K=512 -> 256) ----
  f32x16 a3a = zero16(), a3b = zero16();
  const int j2a = w >> 1, j2b = (w >> 1) + 4;
  // half 0: H2 cols 0..255 (tiles jt1 = w)
  store_tile<true>(a2_00, H2r, S2, 0,  w * 32, b1 + w * 32, lane);
  store_tile<true>(a2_01, H2r, S2, 32, w * 32, b1 + w * 32, lane);
  __syncthreads();
  {
    const _Float16* hb = H2r + (size_t)(mt * 32 + m31) * S2 + s8;
    const _Float16* wa = W2p + ((size_t)(j2a * 32) * 64 + lane) * 8;
    const _Float16* wb2 = W2p + ((size_t)(j2b * 32) * 64 + lane) * 8;
#pragma unroll 2
    for (int kt = 0; kt < 16; ++kt) {
      half8 A0 = *(const half8*)(wa + kt * 512);
      half8 A1 = *(const half8*)(wb2 + kt * 512);
      half8 B = *(const half8*)(hb + kt * 16);
      a3a = MFMA(A0, B, a3a);
      a3b = MFMA(A1, B, a3b);
    }
  }
  __syncthreads();
  // half 1: H2 cols 256..511 (tiles jt1 = w+8)
  store_tile<true>(a2_10, H2r, S2, 0,  w * 32, b1 + 256 + w * 32, lane);
  store_tile<true>(a2_11, H2r, S2, 32, w * 32, b1 + 256 + w * 32, lane);
  __syncthreads();
  {
    const _Float16* hb = H2r + (size_t)(mt * 32 + m31) * S2 + s8;
    const _Float16* wa = W2p + ((size_t)(j2a * 32 + 16) * 64 + lane) * 8;
    const _Float16* wb2 = W2p + ((size_t)(j2b * 32 + 16) * 64 + lane) * 8;
#pragma unroll 2
    for (int kt = 0; kt < 16; ++kt) {
      half8 A0 = *(const half8*)(wa + kt * 512);
      half8 A1 = *(const half8*)(wb2 + kt * 512);
      half8 B = *(const half8*)(hb + kt * 16);
      a3a = MFMA(A0, B, a3a);
      a3b = MFMA(A1, B, a3b);
    }
  }
  // H3 region disjoint from H2r -> no barrier needed before these stores
  store_tile<true>(a3a, H3r, S2, mt * 32, j2a * 32, b2 + j2a * 32, lane);
  store_tile<true>(a3b, H3r, S2, mt * 32, j2b * 32, b2 + j2b * 32, lane);
  __syncthreads();

  // ---- L3: K=256 -> 128 ----
  {
    const int j3 = w >> 1;   // 0..3
    f32x16 a4 = zero16();
    const _Float16* hb = H3r + (size_t)(mt * 32 + m31) * S2 + s8;
    const _Float16* wb3 = W3p + ((size_t)(j3 * 16) * 64 + lane) * 8;
#pragma unroll 2
    for (int kt = 0; kt < 16; ++kt) {
      half8 A = *(const half8*)(wb3 + kt * 512);
      half8 B = *(const half8*)(hb + kt * 16);
      a4 = MFMA(A, B, a4);
    }
    store_tile<true>(a4, H4r, S4, mt * 32, j3 * 32, b3 + j3 * 32, lane);
  }
  __syncthreads();

  // ---- L4: [64][128] @ W4^T -> [64][2] ----
  {
    const int m = tid >> 3;
    const int sub = tid & 7;
    const int j = sub & 1;
    const int q = sub >> 1;
    const _Float16* h4 = H4r + (size_t)m * S4 + q * 32;
    const float* w4 = W4 + j * CC + q * 32;
    float s = 0.f;
#pragma unroll
    for (int cc = 0; cc < 32; ++cc) s += (float)h4[cc] * w4[cc];
    s += __shfl_xor(s, 2);
    s += __shfl_xor(s, 4);
    if (q == 0) preds[(size_t)(m0 + m) * 2 + j] = s + b4[j];
  }
}

// ---------- softmax-combine over the 4 samples ----------
__global__ void jiif_combine(const float* __restrict__ preds, float* __restrict__ out) {
  const int i = blockIdx.x * 256 + threadIdx.x;
  if (i >= BN * NN) return;
  float p0[4], p1[4];
#pragma unroll
  for (int k = 0; k < 4; ++k) {
    p0[k] = preds[((size_t)k * BN * NN + i) * 2 + 0];
    p1[k] = preds[((size_t)k * BN * NN + i) * 2 + 1];
  }
  float mx = fmaxf(fmaxf(p1[0], p1[1]), fmaxf(p1[2], p1[3]));
  float se = 0.f, so = 0.f;
#pragma unroll
  for (int k = 0; k < 4; ++k) {
    float e = expf(p1[k] - mx);
    se += e;
    so += p0[k] * e;
  }
  out[i] = so / se;
}

extern "C" void kernel_launch(void* const* d_in, const int* in_sizes, int n_in,
                              void* d_out, int out_size, void* d_ws, size_t ws_size,
                              hipStream_t stream) {
  const float* feat  = (const float*)d_in[0];
  const float* coord = (const float*)d_in[1];
  const float* hr    = (const float*)d_in[2];
  const float* lr    = (const float*)d_in[3];
  const float* W0 = (const float*)d_in[4];  const float* b0 = (const float*)d_in[5];
  const float* W1 = (const float*)d_in[6];  const float* b1 = (const float*)d_in[7];
  const float* W2 = (const float*)d_in[8];  const float* b2 = (const float*)d_in[9];
  const float* W3 = (const float*)d_in[10]; const float* b3 = (const float*)d_in[11];
  const float* W4 = (const float*)d_in[12]; const float* b4 = (const float*)d_in[13];

  char* ws = (char*)d_ws;
  _Float16* W0p   = (_Float16*)(ws + 0);          // 32*26*512*2  =   851968
  _Float16* W1p   = (_Float16*)(ws + 851968);     // 16*64*512*2  =  1048576
  _Float16* W2p   = (_Float16*)(ws + 1900544);    // 8*32*512*2   =   262144
  _Float16* W3p   = (_Float16*)(ws + 2162688);    // 4*16*512*2   =    65536
  _Float16* featT = (_Float16*)(ws + 2228224);    // 2097152
  _Float16* hrT   = (_Float16*)(ws + 4325376);    // 33554432
  _Float16* lrT   = (_Float16*)(ws + 37879808);   // 2097152
  float* preds    = (float*)(ws + 39976960);      // 1048576 -> total 41025536
  if (ws_size < 41025536) return;

  pack_w<<<208, 256, 0, stream>>>(W0, W0p, 32, 386, 26);
  pack_w<<<256, 256, 0, stream>>>(W1, W1p, 16, 1024, 64);
  pack_w<<<64,  256, 0, stream>>>(W2, W2p, 8, 512, 32);
  pack_w<<<16,  256, 0, stream>>>(W3, W3p, 4, 256, 16);

  transpose_to_hwc<<<dim3(2, 4, 128), dim3(32, 8), 0, stream>>>(feat, featT, CC, FH, FW);
  transpose_to_hwc<<<dim3(8, 4, 512), dim3(32, 8), 0, stream>>>(hr,   hrT,   CC, GH, GW);
  transpose_to_hwc<<<dim3(2, 4, 128), dim3(32, 8), 0, stream>>>(lr,   lrT,   CC, FH, FW);

  (void)hipFuncSetAttribute((const void*)jiif_main,
                            hipFuncAttributeMaxDynamicSharedMemorySize, LDS_ELEMS * 2);
  jiif_main<<<NBLK, 512, LDS_ELEMS * 2, stream>>>(
      coord, featT, hrT, lrT, W0p, W1p, W2p, W3p, b0, b1, b2, b3, W4, b4, preds);

  jiif_combine<<<(BN * NN + 255) / 256, 256, 0, stream>>>(preds, (float*)d_out);
}

// Round 4
// 373.091 us; speedup vs baseline: 1.0113x; 1.0113x over previous
//
#include <hip/hip_runtime.h>
#include <cstdint>

typedef __attribute__((ext_vector_type(8))) _Float16 half8;   // 8 fp16 = 4 VGPRs
typedef __attribute__((ext_vector_type(16))) float   f32x16;  // 32x32 MFMA acc

#define BN 2
#define NN 16384
#define FH 64
#define FW 64
#define GH 256
#define GW 256
#define CC 128
#define M_TOTAL (4*BN*NN)    // 131072
#define MROWS 64
#define NBLK (M_TOTAL/MROWS) // 2048

// LDS strides (fp16 elems); dword-stride % 32 == 4 -> benign bank pattern for b128
#define SX  456              // X [64][448+pad]
#define SC  264              // Hc (H1 chunk) [64][256+pad]
#define S2H 520              // H2 [64][512+pad]
#define S3  264              // H3 [64][256+pad]
#define S4  136              // H4 [64][128+pad]
#define OFF_HC 29184         // 64*SX
#define OFF_H3 33280         // 64*S2H (H3 after H2 overlay)
#define LDS_ELEMS 50176      // max(OFF_HC+64*SC, OFF_H3+64*S3) = 50176 elems = 100352 B

#define MFMA(a,b,c) __builtin_amdgcn_mfma_f32_32x32x16_f16((a),(b),(c),0,0,0)

static __device__ __forceinline__ f32x16 zero16() {
  f32x16 z;
#pragma unroll
  for (int i = 0; i < 16; ++i) z[i] = 0.f;
  return z;
}
static __device__ __forceinline__ half8 zero8() {
  half8 z;
#pragma unroll
  for (int e = 0; e < 8; ++e) z[e] = (_Float16)0.f;
  return z;
}

// ---------- weight fp32 -> packed fp16 32x16 MFMA A-fragment tiles ----------
// out[((jt*KT+kt)*64 + l)*8 + e] = W[jt*32 + (l&31)][kt*16 + (l>>5)*8 + e]
__global__ void pack_w(const float* __restrict__ wsrc, _Float16* __restrict__ out,
                       int NT, int K, int KT) {   // NT = NOUT/32
  int idx = blockIdx.x * 256 + threadIdx.x;
  int total = NT * KT * 64;
  if (idx >= total) return;
  int l = idx & 63;
  int t = idx >> 6;
  int kt = t % KT;
  int jt = t / KT;
  int row = jt * 32 + (l & 31);
  int k0 = kt * 16 + (l >> 5) * 8;
  _Float16* o = out + (size_t)idx * 8;
#pragma unroll
  for (int e = 0; e < 8; ++e) {
    int k = k0 + e;
    float v = (k < K) ? wsrc[(size_t)row * K + k] : 0.f;
    o[e] = (_Float16)v;
  }
}

// ---------- CHW -> HWC fp16 transpose ----------
__global__ void transpose_to_hwc(const float* __restrict__ in, _Float16* __restrict__ out,
                                 int C, int HH, int WW) {
  __shared__ float tile[32][33];
  const int xt = blockIdx.x, ct = blockIdx.y;
  const int bb = blockIdx.z / HH, y = blockIdx.z % HH;
  const int tx = threadIdx.x, ty = threadIdx.y;
  const int x0 = xt * 32, c0 = ct * 32;
#pragma unroll
  for (int i = 0; i < 4; ++i) {
    int c = c0 + ty + i * 8;
    tile[ty + i * 8][tx] = in[((size_t)(bb * C + c) * HH + y) * WW + x0 + tx];
  }
  __syncthreads();
#pragma unroll
  for (int i = 0; i < 4; ++i) {
    int x = x0 + ty + i * 8;
    out[((size_t)(bb * HH + y) * WW + x) * C + c0 + tx] = (_Float16)tile[tx][ty + i * 8];
  }
}

// ---------- store one 32x32 D-tile to LDS, bias+relu, 8B-vectorized ----------
// D layout (A=W, B=acts): act-row m = lane&31, out-ch n = (reg&3)+8*(reg>>2)+4*(lane>>5)
template<bool RELU>
static __device__ __forceinline__ void store_tile(const f32x16 acc, _Float16* lout, int ldo,
                                                  int row0, int col0,
                                                  const float* __restrict__ biasBase, int lane) {
  const int m = row0 + (lane & 31);
  const int s4 = (lane >> 5) * 4;
  _Float16* rp = lout + (size_t)m * ldo + col0 + s4;
  const float* bp = biasBase + s4;
#pragma unroll
  for (int g = 0; g < 4; ++g) {
    float4 bv = *(const float4*)(bp + 8 * g);
    union { _Float16 h[4]; unsigned long long u; } pk;
#pragma unroll
    for (int e = 0; e < 4; ++e) {
      float v = acc[4 * g + e] + ((const float*)&bv)[e];
      if (RELU) v = fmaxf(v, 0.f);
      pk.h[e] = (_Float16)v;
    }
    *(unsigned long long*)(rp + 8 * g) = pk.u;
  }
}

// ---------- fused main kernel: 1 block/CU, 8 waves, deep-batched prefetch ----------
__global__ __launch_bounds__(512, 2) void jiif_main(
    const float* __restrict__ coord,
    const _Float16* __restrict__ featT, const _Float16* __restrict__ hrT,
    const _Float16* __restrict__ lrT,
    const _Float16* __restrict__ W0p, const _Float16* __restrict__ W1p,
    const _Float16* __restrict__ W2p, const _Float16* __restrict__ W3p,
    const float* __restrict__ b0, const float* __restrict__ b1,
    const float* __restrict__ b2, const float* __restrict__ b3,
    const float* __restrict__ W4, const float* __restrict__ b4,
    float* __restrict__ preds) {
  extern __shared__ _Float16 lds[];
  const int tid = threadIdx.x;
  const int w = tid >> 6, lane = tid & 63;
  const int m0 = blockIdx.x * MROWS;
  _Float16* X   = lds;             // [64][SX]
  _Float16* Hc  = lds + OFF_HC;    // [64][SC]
  _Float16* H2r = lds;             // [64][S2H] (overlays X after L0/L1)
  _Float16* H3r = lds + OFF_H3;    // [64][S3]
  _Float16* H4r = lds;             // [64][S4]

  // ---- gather: build X[64][448] (cols 386..448 zero) ----
  {
    const int r = tid >> 3;       // 0..63
    const int g = tid & 7;        // 8 threads per row
    const int row = m0 + r;
    const int n = row & (NN - 1);
    const int bb = (row >> 14) & (BN - 1);
    const int k = row >> 15;      // offset index 0..3
    const float c0 = coord[((size_t)bb * NN + n) * 2 + 0];
    const float c1 = coord[((size_t)bb * NN + n) * 2 + 1];
    const float cy = c0 + ((k < 2) ? -1.f : 1.f) * (1.f / FH);
    const float cx = c1 + ((k & 1) ? 1.f : -1.f) * (1.f / FW);
    const float fy = rintf((cy + 1.f) * (FH * 0.5f) - 0.5f);
    const float fx = rintf((cx + 1.f) * (FW * 0.5f) - 0.5f);
    const bool vF = (fy >= 0.f) && (fy < (float)FH) && (fx >= 0.f) && (fx < (float)FW);
    const int iy = max(0, min(FH - 1, (int)fy));
    const int ix = max(0, min(FW - 1, (int)fx));
    const float gy = rintf((c0 + 1.f) * (GH * 0.5f) - 0.5f);
    const float gx = rintf((c1 + 1.f) * (GW * 0.5f) - 0.5f);
    const bool vH = (gy >= 0.f) && (gy < (float)GH) && (gx >= 0.f) && (gx < (float)GW);
    const int jy = max(0, min(GH - 1, (int)gy));
    const int jx = max(0, min(GW - 1, (int)gx));
    const _Float16* fp = featT + (size_t)((bb * FH + iy) * FW + ix) * CC;
    const _Float16* lp = lrT  + (size_t)((bb * FH + iy) * FW + ix) * CC;
    const _Float16* hp = hrT  + (size_t)((bb * GH + jy) * GW + jx) * CC;
    _Float16* xr = X + (size_t)r * SX;
#pragma unroll
    for (int t = 0; t < 2; ++t) {
      const int c8 = g * 16 + t * 8;
      half8 fv = vF ? *(const half8*)(fp + c8) : zero8();
      half8 lv = vF ? *(const half8*)(lp + c8) : zero8();
      half8 hv = vH ? *(const half8*)(hp + c8) : zero8();
      *(half8*)(xr + c8) = fv;
      *(half8*)(xr + CC + c8) = hv;
      half8 dv = hv - lv;
      *(half8*)(xr + 2 * CC + c8) = dv;
    }
    // zero-pad cols 384..448 (8 threads x 8 elems), then rel coords
    *(unsigned long long*)(xr + 384 + g * 8) = 0ull;
    *(unsigned long long*)(xr + 384 + g * 8 + 4) = 0ull;
    if (g == 0) {
      const float qc0 = vF ? (-1.f + (float)(2 * iy + 1) * (1.f / FH)) : 0.f;
      const float qc1 = vF ? (-1.f + (float)(2 * ix + 1) * (1.f / FW)) : 0.f;
      xr[384] = (_Float16)((c0 - qc0) * (float)FH);
      xr[385] = (_Float16)((c1 - qc1) * (float)FW);
    }
  }
  __syncthreads();

  const int m31 = lane & 31;
  const int s8 = (lane >> 5) * 8;
  const _Float16* xb0 = X + (size_t)m31 * SX + s8;          // act rows 0..31
  const _Float16* xb1 = X + (size_t)(32 + m31) * SX + s8;   // act rows 32..63

  // ---- fused L0 (4 chunks of 256 cols) -> L1 (K-chunks of 256) ----
  f32x16 a2_00 = zero16(), a2_01 = zero16(), a2_10 = zero16(), a2_11 = zero16();
#pragma unroll 1
  for (int c = 0; c < 4; ++c) {
    // L0: wave owns j-tile (c*8 + w), both mt. 28 kt in 4 batches of 7.
    f32x16 a0lo = zero16(), a0hi = zero16();
    {
      const _Float16* wb = W0p + ((size_t)(c * 8 + w) * 28 * 64 + lane) * 8;
#pragma unroll 1
      for (int t = 0; t < 4; ++t) {
        half8 A[7], B0[7], B1[7];
#pragma unroll
        for (int i = 0; i < 7; ++i) {
          const int kt = t * 7 + i;
          A[i]  = *(const half8*)(wb + kt * 512);
          B0[i] = *(const half8*)(xb0 + kt * 16);
          B1[i] = *(const half8*)(xb1 + kt * 16);
        }
        __builtin_amdgcn_s_setprio(1);
#pragma unroll
        for (int i = 0; i < 7; ++i) {
          a0lo = MFMA(A[i], B0[i], a0lo);
          a0hi = MFMA(A[i], B1[i], a0hi);
        }
        __builtin_amdgcn_s_setprio(0);
      }
    }
    store_tile<true>(a0lo, Hc, SC, 0,  w * 32, b0 + c * 256 + w * 32, lane);
    store_tile<true>(a0hi, Hc, SC, 32, w * 32, b0 + c * 256 + w * 32, lane);
    __syncthreads();
    // L1 partial: K-range [c*256, c*256+256). A tiles j1 = w and w+8.
    {
      const _Float16* w1a = W1p + ((size_t)(w * 64 + c * 16) * 64 + lane) * 8;
      const _Float16* w1b = W1p + ((size_t)((w + 8) * 64 + c * 16) * 64 + lane) * 8;
      const _Float16* hb0 = Hc + (size_t)m31 * SC + s8;
      const _Float16* hb1 = Hc + (size_t)(32 + m31) * SC + s8;
#pragma unroll 1
      for (int t = 0; t < 4; ++t) {
        half8 A0[4], A1[4], B0[4], B1[4];
#pragma unroll
        for (int i = 0; i < 4; ++i) {
          const int kt = t * 4 + i;
          A0[i] = *(const half8*)(w1a + kt * 512);
          A1[i] = *(const half8*)(w1b + kt * 512);
          B0[i] = *(const half8*)(hb0 + kt * 16);
          B1[i] = *(const half8*)(hb1 + kt * 16);
        }
        __builtin_amdgcn_s_setprio(1);
#pragma unroll
        for (int i = 0; i < 4; ++i) {
          a2_00 = MFMA(A0[i], B0[i], a2_00);
          a2_01 = MFMA(A0[i], B1[i], a2_01);
          a2_10 = MFMA(A1[i], B0[i], a2_10);
          a2_11 = MFMA(A1[i], B1[i], a2_11);
        }
        __builtin_amdgcn_s_setprio(0);
      }
    }
    __syncthreads();
  }

  // ---- H2 store (overlays X region) ----
  store_tile<true>(a2_00, H2r, S2H, 0,  w * 32,       b1 + w * 32,       lane);
  store_tile<true>(a2_01, H2r, S2H, 32, w * 32,       b1 + w * 32,       lane);
  store_tile<true>(a2_10, H2r, S2H, 0,  256 + w * 32, b1 + 256 + w * 32, lane);
  store_tile<true>(a2_11, H2r, S2H, 32, 256 + w * 32, b1 + 256 + w * 32, lane);
  __syncthreads();

  // ---- L2: K=512 -> 256. wave: j2 = w, both mt. 32 kt in 4 batches of 8. ----
  {
    f32x16 a3lo = zero16(), a3hi = zero16();
    const _Float16* wb = W2p + ((size_t)(w * 32) * 64 + lane) * 8;
    const _Float16* hb0 = H2r + (size_t)m31 * S2H + s8;
    const _Float16* hb1 = H2r + (size_t)(32 + m31) * S2H + s8;
#pragma unroll 1
    for (int t = 0; t < 4; ++t) {
      half8 A[8], B0[8], B1[8];
#pragma unroll
      for (int i = 0; i < 8; ++i) {
        const int kt = t * 8 + i;
        A[i]  = *(const half8*)(wb + kt * 512);
        B0[i] = *(const half8*)(hb0 + kt * 16);
        B1[i] = *(const half8*)(hb1 + kt * 16);
      }
      __builtin_amdgcn_s_setprio(1);
#pragma unroll
      for (int i = 0; i < 8; ++i) {
        a3lo = MFMA(A[i], B0[i], a3lo);
        a3hi = MFMA(A[i], B1[i], a3hi);
      }
      __builtin_amdgcn_s_setprio(0);
    }
    // H3 region disjoint from H2 -> safe to store before barrier
    store_tile<true>(a3lo, H3r, S3, 0,  w * 32, b2 + w * 32, lane);
    store_tile<true>(a3hi, H3r, S3, 32, w * 32, b2 + w * 32, lane);
  }
  __syncthreads();

  // ---- L3: K=256 -> 128. wave: j3 = w&3, mt = w>>2. 16 kt in 2 batches of 8. ----
  {
    const int j3 = w & 3, mts = w >> 2;
    f32x16 a4 = zero16();
    const _Float16* wb = W3p + ((size_t)(j3 * 16) * 64 + lane) * 8;
    const _Float16* hb = H3r + (size_t)(mts * 32 + m31) * S3 + s8;
#pragma unroll 1
    for (int t = 0; t < 2; ++t) {
      half8 A[8], B[8];
#pragma unroll
      for (int i = 0; i < 8; ++i) {
        const int kt = t * 8 + i;
        A[i] = *(const half8*)(wb + kt * 512);
        B[i] = *(const half8*)(hb + kt * 16);
      }
      __builtin_amdgcn_s_setprio(1);
#pragma unroll
      for (int i = 0; i < 8; ++i) a4 = MFMA(A[i], B[i], a4);
      __builtin_amdgcn_s_setprio(0);
    }
    store_tile<true>(a4, H4r, S4, mts * 32, j3 * 32, b3 + j3 * 32, lane);
  }
  __syncthreads();

  // ---- L4: [64][128] @ W4^T -> [64][2] ----
  {
    const int m = tid >> 3;
    const int sub = tid & 7;
    const int j = sub & 1;
    const int q = sub >> 1;
    const _Float16* h4 = H4r + (size_t)m * S4 + q * 32;
    const float* w4 = W4 + j * CC + q * 32;
    float s = 0.f;
#pragma unroll
    for (int cc = 0; cc < 32; ++cc) s += (float)h4[cc] * w4[cc];
    s += __shfl_xor(s, 2);
    s += __shfl_xor(s, 4);
    if (q == 0) preds[(size_t)(m0 + m) * 2 + j] = s + b4[j];
  }
}

// ---------- softmax-combine over the 4 samples ----------
__global__ void jiif_combine(const float* __restrict__ preds, float* __restrict__ out) {
  const int i = blockIdx.x * 256 + threadIdx.x;
  if (i >= BN * NN) return;
  float p0[4], p1[4];
#pragma unroll
  for (int k = 0; k < 4; ++k) {
    p0[k] = preds[((size_t)k * BN * NN + i) * 2 + 0];
    p1[k] = preds[((size_t)k * BN * NN + i) * 2 + 1];
  }
  float mx = fmaxf(fmaxf(p1[0], p1[1]), fmaxf(p1[2], p1[3]));
  float se = 0.f, so = 0.f;
#pragma unroll
  for (int k = 0; k < 4; ++k) {
    float e = expf(p1[k] - mx);
    se += e;
    so += p0[k] * e;
  }
  out[i] = so / se;
}

extern "C" void kernel_launch(void* const* d_in, const int* in_sizes, int n_in,
                              void* d_out, int out_size, void* d_ws, size_t ws_size,
                              hipStream_t stream) {
  const float* feat  = (const float*)d_in[0];
  const float* coord = (const float*)d_in[1];
  const float* hr    = (const float*)d_in[2];
  const float* lr    = (const float*)d_in[3];
  const float* W0 = (const float*)d_in[4];  const float* b0 = (const float*)d_in[5];
  const float* W1 = (const float*)d_in[6];  const float* b1 = (const float*)d_in[7];
  const float* W2 = (const float*)d_in[8];  const float* b2 = (const float*)d_in[9];
  const float* W3 = (const float*)d_in[10]; const float* b3 = (const float*)d_in[11];
  const float* W4 = (const float*)d_in[12]; const float* b4 = (const float*)d_in[13];

  char* ws = (char*)d_ws;
  _Float16* W0p   = (_Float16*)(ws + 0);          // 32*28*512*2  =   917504
  _Float16* W1p   = (_Float16*)(ws + 917504);     // 16*64*512*2  =  1048576
  _Float16* W2p   = (_Float16*)(ws + 1966080);    // 8*32*512*2   =   262144
  _Float16* W3p   = (_Float16*)(ws + 2228224);    // 4*16*512*2   =    65536
  _Float16* featT = (_Float16*)(ws + 2293760);    // 2097152
  _Float16* hrT   = (_Float16*)(ws + 4390912);    // 33554432
  _Float16* lrT   = (_Float16*)(ws + 37945344);   // 2097152
  float* preds    = (float*)(ws + 40042496);      // 1048576 -> total 41091072
  if (ws_size < 41091072) return;

  pack_w<<<224, 256, 0, stream>>>(W0, W0p, 32, 386, 28);
  pack_w<<<256, 256, 0, stream>>>(W1, W1p, 16, 1024, 64);
  pack_w<<<64,  256, 0, stream>>>(W2, W2p, 8, 512, 32);
  pack_w<<<16,  256, 0, stream>>>(W3, W3p, 4, 256, 16);

  transpose_to_hwc<<<dim3(2, 4, 128), dim3(32, 8), 0, stream>>>(feat, featT, CC, FH, FW);
  transpose_to_hwc<<<dim3(8, 4, 512), dim3(32, 8), 0, stream>>>(hr,   hrT,   CC, GH, GW);
  transpose_to_hwc<<<dim3(2, 4, 128), dim3(32, 8), 0, stream>>>(lr,   lrT,   CC, FH, FW);

  (void)hipFuncSetAttribute((const void*)jiif_main,
                            hipFuncAttributeMaxDynamicSharedMemorySize, LDS_ELEMS * 2);
  jiif_main<<<NBLK, 512, LDS_ELEMS * 2, stream>>>(
      coord, featT, hrT, lrT, W0p, W1p, W2p, W3p, b0, b1, b2, b3, W4, b4, preds);

  jiif_combine<<<(BN * NN + 255) / 256, 256, 0, stream>>>(preds, (float*)d_out);
}

// Round 5
// 359.364 us; speedup vs baseline: 1.0499x; 1.0382x over previous
//
#include <hip/hip_runtime.h>
#include <cstdint>

typedef __attribute__((ext_vector_type(8))) _Float16 half8;   // 8 fp16 = 4 VGPRs
typedef __attribute__((ext_vector_type(16))) float   f32x16;  // 32x32 MFMA acc

#define BN 2
#define NN 16384
#define FH 64
#define FW 64
#define GH 256
#define GW 256
#define CC 128
#define M_TOTAL (4*BN*NN)    // 131072
#define MROWS 64
#define NBLK (M_TOTAL/MROWS) // 2048

// LDS strides (fp16 elems); dword-stride % 32 == 4 -> benign bank pattern for b128
#define SX  456              // X [64][448+pad]
#define SC  264              // Hc (H1 chunk) [64][256+pad]
#define S2H 520              // H2 [64][512+pad]
#define S3  264              // H3 [64][256+pad]
#define S4  136              // H4 [64][128+pad]
#define OFF_HC 29184         // 64*SX
#define OFF_H3 33280         // 64*S2H (H3 after H2 overlay)
#define LDS_ELEMS 50176      // 100352 B -> 1 block/CU

#define MFMA(a,b,c) __builtin_amdgcn_mfma_f32_32x32x16_f16((a),(b),(c),0,0,0)

static __device__ __forceinline__ f32x16 zero16() {
  f32x16 z;
#pragma unroll
  for (int i = 0; i < 16; ++i) z[i] = 0.f;
  return z;
}
static __device__ __forceinline__ half8 zero8() {
  half8 z;
#pragma unroll
  for (int e = 0; e < 8; ++e) z[e] = (_Float16)0.f;
  return z;
}

// ---- pipelined-batch helpers: load batch of 4 kt into named reg set, pinned MFMA burst ----
// Pattern: A from global (vmcnt), B from LDS (lgkmcnt). sched_barrier(0) fences keep the
// load batch ABOVE the burst so waitcnts are counted (vmcnt(4)/lgkmcnt(8)), not drain-all.

static __device__ __forceinline__ void ld_ab2(half8 (&A)[4], half8 (&B0)[4], half8 (&B1)[4],
    const _Float16* wb, const _Float16* xb0, const _Float16* xb1, int t) {
#pragma unroll
  for (int i = 0; i < 4; ++i) {
    const int kt = t * 4 + i;
    A[i]  = *(const half8*)(wb  + kt * 512);
    B0[i] = *(const half8*)(xb0 + kt * 16);
    B1[i] = *(const half8*)(xb1 + kt * 16);
  }
}
static __device__ __forceinline__ void mm_ab2(f32x16& lo, f32x16& hi,
    const half8 (&A)[4], const half8 (&B0)[4], const half8 (&B1)[4]) {
  __builtin_amdgcn_sched_barrier(0);
  __builtin_amdgcn_s_setprio(1);
#pragma unroll
  for (int i = 0; i < 4; ++i) {
    lo = MFMA(A[i], B0[i], lo);
    hi = MFMA(A[i], B1[i], hi);
  }
  __builtin_amdgcn_s_setprio(0);
  __builtin_amdgcn_sched_barrier(0);
}

static __device__ __forceinline__ void ld_a2b2(half8 (&A0)[4], half8 (&A1)[4],
    half8 (&B0)[4], half8 (&B1)[4],
    const _Float16* wa, const _Float16* wb, const _Float16* xb0, const _Float16* xb1, int t) {
#pragma unroll
  for (int i = 0; i < 4; ++i) {
    const int kt = t * 4 + i;
    A0[i] = *(const half8*)(wa + kt * 512);
    A1[i] = *(const half8*)(wb + kt * 512);
    B0[i] = *(const half8*)(xb0 + kt * 16);
    B1[i] = *(const half8*)(xb1 + kt * 16);
  }
}
static __device__ __forceinline__ void mm_a2b2(f32x16& a00, f32x16& a01, f32x16& a10, f32x16& a11,
    const half8 (&A0)[4], const half8 (&A1)[4], const half8 (&B0)[4], const half8 (&B1)[4]) {
  __builtin_amdgcn_sched_barrier(0);
  __builtin_amdgcn_s_setprio(1);
#pragma unroll
  for (int i = 0; i < 4; ++i) {
    a00 = MFMA(A0[i], B0[i], a00);
    a01 = MFMA(A0[i], B1[i], a01);
    a10 = MFMA(A1[i], B0[i], a10);
    a11 = MFMA(A1[i], B1[i], a11);
  }
  __builtin_amdgcn_s_setprio(0);
  __builtin_amdgcn_sched_barrier(0);
}

static __device__ __forceinline__ void ld_ab1(half8 (&A)[4], half8 (&B)[4],
    const _Float16* wb, const _Float16* xb, int t) {
#pragma unroll
  for (int i = 0; i < 4; ++i) {
    const int kt = t * 4 + i;
    A[i] = *(const half8*)(wb + kt * 512);
    B[i] = *(const half8*)(xb + kt * 16);
  }
}
static __device__ __forceinline__ void mm_ab1(f32x16& acc,
    const half8 (&A)[4], const half8 (&B)[4]) {
  __builtin_amdgcn_sched_barrier(0);
  __builtin_amdgcn_s_setprio(1);
#pragma unroll
  for (int i = 0; i < 4; ++i) acc = MFMA(A[i], B[i], acc);
  __builtin_amdgcn_s_setprio(0);
  __builtin_amdgcn_sched_barrier(0);
}

// ---------- weight fp32 -> packed fp16 32x16 MFMA A-fragment tiles ----------
__global__ void pack_w(const float* __restrict__ wsrc, _Float16* __restrict__ out,
                       int NT, int K, int KT) {   // NT = NOUT/32
  int idx = blockIdx.x * 256 + threadIdx.x;
  int total = NT * KT * 64;
  if (idx >= total) return;
  int l = idx & 63;
  int t = idx >> 6;
  int kt = t % KT;
  int jt = t / KT;
  int row = jt * 32 + (l & 31);
  int k0 = kt * 16 + (l >> 5) * 8;
  _Float16* o = out + (size_t)idx * 8;
#pragma unroll
  for (int e = 0; e < 8; ++e) {
    int k = k0 + e;
    float v = (k < K) ? wsrc[(size_t)row * K + k] : 0.f;
    o[e] = (_Float16)v;
  }
}

// ---------- CHW -> HWC fp16 transpose ----------
__global__ void transpose_to_hwc(const float* __restrict__ in, _Float16* __restrict__ out,
                                 int C, int HH, int WW) {
  __shared__ float tile[32][33];
  const int xt = blockIdx.x, ct = blockIdx.y;
  const int bb = blockIdx.z / HH, y = blockIdx.z % HH;
  const int tx = threadIdx.x, ty = threadIdx.y;
  const int x0 = xt * 32, c0 = ct * 32;
#pragma unroll
  for (int i = 0; i < 4; ++i) {
    int c = c0 + ty + i * 8;
    tile[ty + i * 8][tx] = in[((size_t)(bb * C + c) * HH + y) * WW + x0 + tx];
  }
  __syncthreads();
#pragma unroll
  for (int i = 0; i < 4; ++i) {
    int x = x0 + ty + i * 8;
    out[((size_t)(bb * HH + y) * WW + x) * C + c0 + tx] = (_Float16)tile[tx][ty + i * 8];
  }
}

// ---------- store one 32x32 D-tile to LDS, bias+relu, 8B-vectorized ----------
// D layout (A=W, B=acts): act-row m = lane&31, out-ch n = (reg&3)+8*(reg>>2)+4*(lane>>5)
template<bool RELU>
static __device__ __forceinline__ void store_tile(const f32x16 acc, _Float16* lout, int ldo,
                                                  int row0, int col0,
                                                  const float* __restrict__ biasBase, int lane) {
  const int m = row0 + (lane & 31);
  const int s4 = (lane >> 5) * 4;
  _Float16* rp = lout + (size_t)m * ldo + col0 + s4;
  const float* bp = biasBase + s4;
#pragma unroll
  for (int g = 0; g < 4; ++g) {
    float4 bv = *(const float4*)(bp + 8 * g);
    union { _Float16 h[4]; unsigned long long u; } pk;
#pragma unroll
    for (int e = 0; e < 4; ++e) {
      float v = acc[4 * g + e] + ((const float*)&bv)[e];
      if (RELU) v = fmaxf(v, 0.f);
      pk.h[e] = (_Float16)v;
    }
    *(unsigned long long*)(rp + 8 * g) = pk.u;
  }
}

// ---------- fused main kernel: 8 waves, 2-deep reg-double-buffered pipeline ----------
__global__ __launch_bounds__(512, 2) void jiif_main(
    const float* __restrict__ coord,
    const _Float16* __restrict__ featT, const _Float16* __restrict__ hrT,
    const _Float16* __restrict__ lrT,
    const _Float16* __restrict__ W0p, const _Float16* __restrict__ W1p,
    const _Float16* __restrict__ W2p, const _Float16* __restrict__ W3p,
    const float* __restrict__ b0, const float* __restrict__ b1,
    const float* __restrict__ b2, const float* __restrict__ b3,
    const float* __restrict__ W4, const float* __restrict__ b4,
    float* __restrict__ preds) {
  extern __shared__ _Float16 lds[];
  const int tid = threadIdx.x;
  const int w = tid >> 6, lane = tid & 63;
  const int m0 = blockIdx.x * MROWS;
  _Float16* X   = lds;             // [64][SX]
  _Float16* Hc  = lds + OFF_HC;    // [64][SC]
  _Float16* H2r = lds;             // [64][S2H] (overlays X after L0/L1)
  _Float16* H3r = lds + OFF_H3;    // [64][S3]
  _Float16* H4r = lds;             // [64][S4]

  // ---- gather: build X[64][448] (cols 386..448 zero) ----
  {
    const int r = tid >> 3;       // 0..63
    const int g = tid & 7;        // 8 threads per row
    const int row = m0 + r;
    const int n = row & (NN - 1);
    const int bb = (row >> 14) & (BN - 1);
    const int k = row >> 15;      // offset index 0..3
    const float c0 = coord[((size_t)bb * NN + n) * 2 + 0];
    const float c1 = coord[((size_t)bb * NN + n) * 2 + 1];
    const float cy = c0 + ((k < 2) ? -1.f : 1.f) * (1.f / FH);
    const float cx = c1 + ((k & 1) ? 1.f : -1.f) * (1.f / FW);
    const float fy = rintf((cy + 1.f) * (FH * 0.5f) - 0.5f);
    const float fx = rintf((cx + 1.f) * (FW * 0.5f) - 0.5f);
    const bool vF = (fy >= 0.f) && (fy < (float)FH) && (fx >= 0.f) && (fx < (float)FW);
    const int iy = max(0, min(FH - 1, (int)fy));
    const int ix = max(0, min(FW - 1, (int)fx));
    const float gy = rintf((c0 + 1.f) * (GH * 0.5f) - 0.5f);
    const float gx = rintf((c1 + 1.f) * (GW * 0.5f) - 0.5f);
    const bool vH = (gy >= 0.f) && (gy < (float)GH) && (gx >= 0.f) && (gx < (float)GW);
    const int jy = max(0, min(GH - 1, (int)gy));
    const int jx = max(0, min(GW - 1, (int)gx));
    const _Float16* fp = featT + (size_t)((bb * FH + iy) * FW + ix) * CC;
    const _Float16* lp = lrT  + (size_t)((bb * FH + iy) * FW + ix) * CC;
    const _Float16* hp = hrT  + (size_t)((bb * GH + jy) * GW + jx) * CC;
    _Float16* xr = X + (size_t)r * SX;
#pragma unroll
    for (int t = 0; t < 2; ++t) {
      const int c8 = g * 16 + t * 8;
      half8 fv = vF ? *(const half8*)(fp + c8) : zero8();
      half8 lv = vF ? *(const half8*)(lp + c8) : zero8();
      half8 hv = vH ? *(const half8*)(hp + c8) : zero8();
      *(half8*)(xr + c8) = fv;
      *(half8*)(xr + CC + c8) = hv;
      half8 dv = hv - lv;
      *(half8*)(xr + 2 * CC + c8) = dv;
    }
    *(unsigned long long*)(xr + 384 + g * 8) = 0ull;
    *(unsigned long long*)(xr + 384 + g * 8 + 4) = 0ull;
    if (g == 0) {
      const float qc0 = vF ? (-1.f + (float)(2 * iy + 1) * (1.f / FH)) : 0.f;
      const float qc1 = vF ? (-1.f + (float)(2 * ix + 1) * (1.f / FW)) : 0.f;
      xr[384] = (_Float16)((c0 - qc0) * (float)FH);
      xr[385] = (_Float16)((c1 - qc1) * (float)FW);
    }
  }
  __syncthreads();

  const int m31 = lane & 31;
  const int s8 = (lane >> 5) * 8;
  const _Float16* xb0 = X + (size_t)m31 * SX + s8;          // act rows 0..31
  const _Float16* xb1 = X + (size_t)(32 + m31) * SX + s8;   // act rows 32..63

  // ---- fused L0 (4 chunks of 256 cols) -> L1 (K-chunks of 256) ----
  f32x16 a2_00 = zero16(), a2_01 = zero16(), a2_10 = zero16(), a2_11 = zero16();
#pragma unroll 1
  for (int c = 0; c < 4; ++c) {
    // L0: wave owns j-tile (c*8 + w), both mt. 28 kt = 7 batches of 4, 2-deep.
    f32x16 a0lo = zero16(), a0hi = zero16();
    {
      const _Float16* wb = W0p + ((size_t)(c * 8 + w) * 28 * 64 + lane) * 8;
      half8 sA[4], sB0[4], sB1[4], tA[4], tB0[4], tB1[4];
      ld_ab2(sA, sB0, sB1, wb, xb0, xb1, 0);
      ld_ab2(tA, tB0, tB1, wb, xb0, xb1, 1); mm_ab2(a0lo, a0hi, sA, sB0, sB1);
      ld_ab2(sA, sB0, sB1, wb, xb0, xb1, 2); mm_ab2(a0lo, a0hi, tA, tB0, tB1);
      ld_ab2(tA, tB0, tB1, wb, xb0, xb1, 3); mm_ab2(a0lo, a0hi, sA, sB0, sB1);
      ld_ab2(sA, sB0, sB1, wb, xb0, xb1, 4); mm_ab2(a0lo, a0hi, tA, tB0, tB1);
      ld_ab2(tA, tB0, tB1, wb, xb0, xb1, 5); mm_ab2(a0lo, a0hi, sA, sB0, sB1);
      ld_ab2(sA, sB0, sB1, wb, xb0, xb1, 6); mm_ab2(a0lo, a0hi, tA, tB0, tB1);
      mm_ab2(a0lo, a0hi, sA, sB0, sB1);
    }
    store_tile<true>(a0lo, Hc, SC, 0,  w * 32, b0 + c * 256 + w * 32, lane);
    store_tile<true>(a0hi, Hc, SC, 32, w * 32, b0 + c * 256 + w * 32, lane);
    __syncthreads();
    // L1 partial: K-range [c*256, +256) = 16 kt = 4 batches of 4, 2-deep.
    {
      const _Float16* w1a = W1p + ((size_t)(w * 64 + c * 16) * 64 + lane) * 8;
      const _Float16* w1b = W1p + ((size_t)((w + 8) * 64 + c * 16) * 64 + lane) * 8;
      const _Float16* hb0 = Hc + (size_t)m31 * SC + s8;
      const _Float16* hb1 = Hc + (size_t)(32 + m31) * SC + s8;
      half8 sA0[4], sA1[4], sB0[4], sB1[4], tA0[4], tA1[4], tB0[4], tB1[4];
      ld_a2b2(sA0, sA1, sB0, sB1, w1a, w1b, hb0, hb1, 0);
      ld_a2b2(tA0, tA1, tB0, tB1, w1a, w1b, hb0, hb1, 1);
      mm_a2b2(a2_00, a2_01, a2_10, a2_11, sA0, sA1, sB0, sB1);
      ld_a2b2(sA0, sA1, sB0, sB1, w1a, w1b, hb0, hb1, 2);
      mm_a2b2(a2_00, a2_01, a2_10, a2_11, tA0, tA1, tB0, tB1);
      ld_a2b2(tA0, tA1, tB0, tB1, w1a, w1b, hb0, hb1, 3);
      mm_a2b2(a2_00, a2_01, a2_10, a2_11, sA0, sA1, sB0, sB1);
      mm_a2b2(a2_00, a2_01, a2_10, a2_11, tA0, tA1, tB0, tB1);
    }
    __syncthreads();
  }

  // ---- H2 store (overlays X region) ----
  store_tile<true>(a2_00, H2r, S2H, 0,  w * 32,       b1 + w * 32,       lane);
  store_tile<true>(a2_01, H2r, S2H, 32, w * 32,       b1 + w * 32,       lane);
  store_tile<true>(a2_10, H2r, S2H, 0,  256 + w * 32, b1 + 256 + w * 32, lane);
  store_tile<true>(a2_11, H2r, S2H, 32, 256 + w * 32, b1 + 256 + w * 32, lane);
  __syncthreads();

  // ---- L2: K=512 -> 256. wave: j2 = w, both mt. 32 kt = 8 batches of 4, 2-deep. ----
  {
    f32x16 a3lo = zero16(), a3hi = zero16();
    const _Float16* wb = W2p + ((size_t)(w * 32) * 64 + lane) * 8;
    const _Float16* hb0 = H2r + (size_t)m31 * S2H + s8;
    const _Float16* hb1 = H2r + (size_t)(32 + m31) * S2H + s8;
    half8 sA[4], sB0[4], sB1[4], tA[4], tB0[4], tB1[4];
    ld_ab2(sA, sB0, sB1, wb, hb0, hb1, 0);
    ld_ab2(tA, tB0, tB1, wb, hb0, hb1, 1); mm_ab2(a3lo, a3hi, sA, sB0, sB1);
    ld_ab2(sA, sB0, sB1, wb, hb0, hb1, 2); mm_ab2(a3lo, a3hi, tA, tB0, tB1);
    ld_ab2(tA, tB0, tB1, wb, hb0, hb1, 3); mm_ab2(a3lo, a3hi, sA, sB0, sB1);
    ld_ab2(sA, sB0, sB1, wb, hb0, hb1, 4); mm_ab2(a3lo, a3hi, tA, tB0, tB1);
    ld_ab2(tA, tB0, tB1, wb, hb0, hb1, 5); mm_ab2(a3lo, a3hi, sA, sB0, sB1);
    ld_ab2(sA, sB0, sB1, wb, hb0, hb1, 6); mm_ab2(a3lo, a3hi, tA, tB0, tB1);
    ld_ab2(tA, tB0, tB1, wb, hb0, hb1, 7); mm_ab2(a3lo, a3hi, sA, sB0, sB1);
    mm_ab2(a3lo, a3hi, tA, tB0, tB1);
    // H3 region disjoint from H2 -> safe to store before barrier
    store_tile<true>(a3lo, H3r, S3, 0,  w * 32, b2 + w * 32, lane);
    store_tile<true>(a3hi, H3r, S3, 32, w * 32, b2 + w * 32, lane);
  }
  __syncthreads();

  // ---- L3: K=256 -> 128. wave: j3 = w&3, mt = w>>2. 16 kt = 4 batches of 4, 2-deep. ----
  {
    const int j3 = w & 3, mts = w >> 2;
    f32x16 a4 = zero16();
    const _Float16* wb = W3p + ((size_t)(j3 * 16) * 64 + lane) * 8;
    const _Float16* hb = H3r + (size_t)(mts * 32 + m31) * S3 + s8;
    half8 sA[4], sB[4], tA[4], tB[4];
    ld_ab1(sA, sB, wb, hb, 0);
    ld_ab1(tA, tB, wb, hb, 1); mm_ab1(a4, sA, sB);
    ld_ab1(sA, sB, wb, hb, 2); mm_ab1(a4, tA, tB);
    ld_ab1(tA, tB, wb, hb, 3); mm_ab1(a4, sA, sB);
    mm_ab1(a4, tA, tB);
    store_tile<true>(a4, H4r, S4, mts * 32, j3 * 32, b3 + j3 * 32, lane);
  }
  __syncthreads();

  // ---- L4: [64][128] @ W4^T -> [64][2] ----
  {
    const int m = tid >> 3;
    const int sub = tid & 7;
    const int j = sub & 1;
    const int q = sub >> 1;
    const _Float16* h4 = H4r + (size_t)m * S4 + q * 32;
    const float* w4 = W4 + j * CC + q * 32;
    float s = 0.f;
#pragma unroll
    for (int cc = 0; cc < 32; ++cc) s += (float)h4[cc] * w4[cc];
    s += __shfl_xor(s, 2);
    s += __shfl_xor(s, 4);
    if (q == 0) preds[(size_t)(m0 + m) * 2 + j] = s + b4[j];
  }
}

// ---------- softmax-combine over the 4 samples ----------
__global__ void jiif_combine(const float* __restrict__ preds, float* __restrict__ out) {
  const int i = blockIdx.x * 256 + threadIdx.x;
  if (i >= BN * NN) return;
  float p0[4], p1[4];
#pragma unroll
  for (int k = 0; k < 4; ++k) {
    p0[k] = preds[((size_t)k * BN * NN + i) * 2 + 0];
    p1[k] = preds[((size_t)k * BN * NN + i) * 2 + 1];
  }
  float mx = fmaxf(fmaxf(p1[0], p1[1]), fmaxf(p1[2], p1[3]));
  float se = 0.f, so = 0.f;
#pragma unroll
  for (int k = 0; k < 4; ++k) {
    float e = expf(p1[k] - mx);
    se += e;
    so += p0[k] * e;
  }
  out[i] = so / se;
}

extern "C" void kernel_launch(void* const* d_in, const int* in_sizes, int n_in,
                              void* d_out, int out_size, void* d_ws, size_t ws_size,
                              hipStream_t stream) {
  const float* feat  = (const float*)d_in[0];
  const float* coord = (const float*)d_in[1];
  const float* hr    = (const float*)d_in[2];
  const float* lr    = (const float*)d_in[3];
  const float* W0 = (const float*)d_in[4];  const float* b0 = (const float*)d_in[5];
  const float* W1 = (const float*)d_in[6];  const float* b1 = (const float*)d_in[7];
  const float* W2 = (const float*)d_in[8];  const float* b2 = (const float*)d_in[9];
  const float* W3 = (const float*)d_in[10]; const float* b3 = (const float*)d_in[11];
  const float* W4 = (const float*)d_in[12]; const float* b4 = (const float*)d_in[13];

  char* ws = (char*)d_ws;
  _Float16* W0p   = (_Float16*)(ws + 0);          // 32*28*512*2  =   917504
  _Float16* W1p   = (_Float16*)(ws + 917504);     // 16*64*512*2  =  1048576
  _Float16* W2p   = (_Float16*)(ws + 1966080);    // 8*32*512*2   =   262144
  _Float16* W3p   = (_Float16*)(ws + 2228224);    // 4*16*512*2   =    65536
  _Float16* featT = (_Float16*)(ws + 2293760);    // 2097152
  _Float16* hrT   = (_Float16*)(ws + 4390912);    // 33554432
  _Float16* lrT   = (_Float16*)(ws + 37945344);   // 2097152
  float* preds    = (float*)(ws + 40042496);      // 1048576 -> total 41091072
  if (ws_size < 41091072) return;

  pack_w<<<224, 256, 0, stream>>>(W0, W0p, 32, 386, 28);
  pack_w<<<256, 256, 0, stream>>>(W1, W1p, 16, 1024, 64);
  pack_w<<<64,  256, 0, stream>>>(W2, W2p, 8, 512, 32);
  pack_w<<<16,  256, 0, stream>>>(W3, W3p, 4, 256, 16);

  transpose_to_hwc<<<dim3(2, 4, 128), dim3(32, 8), 0, stream>>>(feat, featT, CC, FH, FW);
  transpose_to_hwc<<<dim3(8, 4, 512), dim3(32, 8), 0, stream>>>(hr,   hrT,   CC, GH, GW);
  transpose_to_hwc<<<dim3(2, 4, 128), dim3(32, 8), 0, stream>>>(lr,   lrT,   CC, FH, FW);

  (void)hipFuncSetAttribute((const void*)jiif_main,
                            hipFuncAttributeMaxDynamicSharedMemorySize, LDS_ELEMS * 2);
  jiif_main<<<NBLK, 512, LDS_ELEMS * 2, stream>>>(
      coord, featT, hrT, lrT, W0p, W1p, W2p, W3p, b0, b1, b2, b3, W4, b4, preds);

  jiif_combine<<<(BN * NN + 255) / 256, 256, 0, stream>>>(preds, (float*)d_out);
}